// Round 1
// baseline (1037.455 us; speedup 1.0000x reference)
//
#include <hip/hip_runtime.h>
#include <hip/hip_bf16.h>
#include <math.h>

// Problem: B=4, T=2048, C=1024, H=16, D=64
// out = proj( attention( x @ W_attn + b_attn ) ) + b_proj

typedef __bf16 bf16x8 __attribute__((ext_vector_type(8)));
typedef float f32x4 __attribute__((ext_vector_type(4)));

__device__ __forceinline__ f32x4 mfma16(bf16x8 a, bf16x8 b, f32x4 c) {
    return __builtin_amdgcn_mfma_f32_16x16x32_bf16(a, b, c, 0, 0, 0);
}

// ---- cast x (fp32) -> bf16, 8 elems/thread ----
__global__ __launch_bounds__(256) void cast_x_kernel(const float* __restrict__ in,
                                                     __hip_bfloat16* __restrict__ out, int n) {
    int i = (blockIdx.x * 256 + threadIdx.x) * 8;
    if (i >= n) return;
    union { __hip_bfloat16 h[8]; uint4 v; } tmp;
#pragma unroll
    for (int j = 0; j < 8; ++j) tmp.h[j] = __float2bfloat16(in[i + j]);
    *reinterpret_cast<uint4*>(out + i) = tmp.v;
}

// ---- transpose+cast: in[R][Cc] fp32 -> out[Cc][R] bf16 ----
__global__ __launch_bounds__(256) void transpose_cast_kernel(const float* __restrict__ in,
                                                             __hip_bfloat16* __restrict__ out,
                                                             int R, int Cc) {
    __shared__ float tile[32][33];
    int c0 = blockIdx.x * 32, r0 = blockIdx.y * 32;
    int tx = threadIdx.x & 31, ty = threadIdx.x >> 5;  // ty 0..7
#pragma unroll
    for (int i = 0; i < 4; ++i) {
        int r = r0 + ty + i * 8;
        tile[ty + i * 8][tx] = in[(size_t)r * Cc + c0 + tx];
    }
    __syncthreads();
#pragma unroll
    for (int i = 0; i < 4; ++i) {
        int c = c0 + ty + i * 8;
        out[(size_t)c * R + r0 + tx] = __float2bfloat16(tile[tx][ty + i * 8]);
    }
}

// ---- QKV GEMM: A[8192,1024]bf16 x Bt[3072,1024]bf16 + bias ----
// q,k -> [B,H,T,D] bf16 ; v -> transposed [B,H,D,T] bf16
__global__ __launch_bounds__(256) void gemm_qkv_kernel(
    const __hip_bfloat16* __restrict__ A, const __hip_bfloat16* __restrict__ Bt,
    const float* __restrict__ bias,
    __hip_bfloat16* __restrict__ qd, __hip_bfloat16* __restrict__ kd,
    __hip_bfloat16* __restrict__ vtd) {
    const int K = 1024;
    int w = threadIdx.x >> 6, l = threadIdx.x & 63;
    int lr = l & 15, lh = l >> 4;
    int m0 = blockIdx.x * 64 + w * 16;
    int n0 = blockIdx.y * 64;
    f32x4 zero = {0.f, 0.f, 0.f, 0.f};
    f32x4 acc[4] = {zero, zero, zero, zero};
    const __hip_bfloat16* ap = A + (size_t)(m0 + lr) * K + lh * 8;
    const __hip_bfloat16* bp = Bt + (size_t)(n0 + lr) * K + lh * 8;
    for (int k0 = 0; k0 < K; k0 += 32) {
        bf16x8 a = *reinterpret_cast<const bf16x8*>(ap + k0);
#pragma unroll
        for (int nt = 0; nt < 4; ++nt) {
            bf16x8 b = *reinterpret_cast<const bf16x8*>(bp + (size_t)nt * 16 * K + k0);
            acc[nt] = mfma16(a, b, acc[nt]);
        }
    }
#pragma unroll
    for (int nt = 0; nt < 4; ++nt) {
        int n = n0 + nt * 16 + lr;
        float bv = bias[n];
#pragma unroll
        for (int r = 0; r < 4; ++r) {
            int m = m0 + 4 * lh + r;
            int bb = m >> 11, t = m & 2047;
            __hip_bfloat16 hv = __float2bfloat16(acc[nt][r] + bv);
            if (n < 1024) {
                int hh = n >> 6, dd = n & 63;
                qd[(((size_t)bb * 16 + hh) * 2048 + t) * 64 + dd] = hv;
            } else if (n < 2048) {
                int c = n - 1024, hh = c >> 6, dd = c & 63;
                kd[(((size_t)bb * 16 + hh) * 2048 + t) * 64 + dd] = hv;
            } else {
                int c = n - 2048, hh = c >> 6, dd = c & 63;
                vtd[(((size_t)bb * 16 + hh) * 64 + dd) * 2048 + t] = hv;
            }
        }
    }
}

// ---- causal flash attention ----
// q,k: [BH, T, D] bf16 ; vt: [BH, D, T] bf16 ; y: [B, T, C] bf16
__global__ __launch_bounds__(256) void attn_kernel(
    const __hip_bfloat16* __restrict__ q, const __hip_bfloat16* __restrict__ k,
    const __hip_bfloat16* __restrict__ vt, __hip_bfloat16* __restrict__ y) {
    const int T = 2048, D = 64, C = 1024;
    int bh = blockIdx.y;
    int b = bh >> 4, h = bh & 15;
    int w = threadIdx.x >> 6, l = threadIdx.x & 63;
    int lr = l & 15, lh = l >> 4;
    int q0 = blockIdx.x * 64 + w * 16;
    __shared__ __hip_bfloat16 P[4][16][40];  // per-wave P tile, padded stride (80B, 16B-aligned reads)

    const __hip_bfloat16* qp = q + ((size_t)bh * T + q0 + lr) * D + lh * 8;
    bf16x8 qa0 = *reinterpret_cast<const bf16x8*>(qp);
    bf16x8 qa1 = *reinterpret_cast<const bf16x8*>(qp + 32);

    f32x4 zero = {0.f, 0.f, 0.f, 0.f};
    f32x4 o[4] = {zero, zero, zero, zero};
    float mrun[4], lrun[4];
#pragma unroll
    for (int r = 0; r < 4; ++r) { mrun[r] = -INFINITY; lrun[r] = 0.f; }

    int qmax = q0 + 15;
    for (int kv0 = 0; kv0 <= qmax; kv0 += 32) {
        f32x4 s0 = zero, s1 = zero;
        const __hip_bfloat16* kp = k + ((size_t)bh * T + kv0 + lr) * D + lh * 8;
        s0 = mfma16(qa0, *reinterpret_cast<const bf16x8*>(kp), s0);
        s0 = mfma16(qa1, *reinterpret_cast<const bf16x8*>(kp + 32), s0);
        s1 = mfma16(qa0, *reinterpret_cast<const bf16x8*>(kp + 16 * D), s1);
        s1 = mfma16(qa1, *reinterpret_cast<const bf16x8*>(kp + 16 * D + 32), s1);

        float mx[4];
#pragma unroll
        for (int r = 0; r < 4; ++r) {
            int qq = q0 + 4 * lh + r;
            s0[r] = (kv0 + lr <= qq) ? s0[r] * 0.125f : -INFINITY;
            s1[r] = (kv0 + 16 + lr <= qq) ? s1[r] * 0.125f : -INFINITY;
            mx[r] = fmaxf(s0[r], s1[r]);
        }
#pragma unroll
        for (int d = 1; d < 16; d <<= 1)
#pragma unroll
            for (int r = 0; r < 4; ++r) mx[r] = fmaxf(mx[r], __shfl_xor(mx[r], d, 16));

        float al[4], psum[4];
        f32x4 p0, p1;
#pragma unroll
        for (int r = 0; r < 4; ++r) {
            float mnew = fmaxf(mrun[r], mx[r]);
            al[r] = __expf(mrun[r] - mnew);
            mrun[r] = mnew;
            p0[r] = __expf(s0[r] - mnew);
            p1[r] = __expf(s1[r] - mnew);
            psum[r] = p0[r] + p1[r];
        }
#pragma unroll
        for (int d = 1; d < 16; d <<= 1)
#pragma unroll
            for (int r = 0; r < 4; ++r) psum[r] += __shfl_xor(psum[r], d, 16);
#pragma unroll
        for (int r = 0; r < 4; ++r) lrun[r] = lrun[r] * al[r] + psum[r];
#pragma unroll
        for (int dt = 0; dt < 4; ++dt)
#pragma unroll
            for (int r = 0; r < 4; ++r) o[dt][r] *= al[r];

        // stage P through per-wave LDS to re-layout into A-fragment (wave-internal, no barrier)
#pragma unroll
        for (int r = 0; r < 4; ++r) {
            P[w][4 * lh + r][lr] = __float2bfloat16(p0[r]);
            P[w][4 * lh + r][16 + lr] = __float2bfloat16(p1[r]);
        }
        bf16x8 pa = *reinterpret_cast<const bf16x8*>(&P[w][lr][lh * 8]);
        const __hip_bfloat16* vp = vt + ((size_t)bh * D + lr) * T + kv0 + lh * 8;
#pragma unroll
        for (int dt = 0; dt < 4; ++dt) {
            bf16x8 vb = *reinterpret_cast<const bf16x8*>(vp + (size_t)dt * 16 * T);
            o[dt] = mfma16(pa, vb, o[dt]);
        }
    }

    float inv[4];
#pragma unroll
    for (int r = 0; r < 4; ++r) inv[r] = 1.0f / lrun[r];
#pragma unroll
    for (int dt = 0; dt < 4; ++dt)
#pragma unroll
        for (int r = 0; r < 4; ++r) {
            int qq = q0 + 4 * lh + r;
            y[((size_t)b * T + qq) * C + h * 64 + dt * 16 + lr] = __float2bfloat16(o[dt][r] * inv[r]);
        }
}

// ---- proj GEMM: A[8192,1024]bf16 x Bt[1024,1024]bf16 + bias -> fp32 out ----
__global__ __launch_bounds__(256) void gemm_proj_kernel(
    const __hip_bfloat16* __restrict__ A, const __hip_bfloat16* __restrict__ Bt,
    const float* __restrict__ bias, float* __restrict__ out) {
    const int K = 1024, N = 1024;
    int w = threadIdx.x >> 6, l = threadIdx.x & 63;
    int lr = l & 15, lh = l >> 4;
    int m0 = blockIdx.x * 64 + w * 16;
    int n0 = blockIdx.y * 64;
    f32x4 zero = {0.f, 0.f, 0.f, 0.f};
    f32x4 acc[4] = {zero, zero, zero, zero};
    const __hip_bfloat16* ap = A + (size_t)(m0 + lr) * K + lh * 8;
    const __hip_bfloat16* bp = Bt + (size_t)(n0 + lr) * K + lh * 8;
    for (int k0 = 0; k0 < K; k0 += 32) {
        bf16x8 a = *reinterpret_cast<const bf16x8*>(ap + k0);
#pragma unroll
        for (int nt = 0; nt < 4; ++nt) {
            bf16x8 b = *reinterpret_cast<const bf16x8*>(bp + (size_t)nt * 16 * K + k0);
            acc[nt] = mfma16(a, b, acc[nt]);
        }
    }
#pragma unroll
    for (int nt = 0; nt < 4; ++nt) {
        int n = n0 + nt * 16 + lr;
        float bv = bias[n];
#pragma unroll
        for (int r = 0; r < 4; ++r) {
            int m = m0 + 4 * lh + r;
            out[(size_t)m * N + n] = acc[nt][r] + bv;
        }
    }
}

extern "C" void kernel_launch(void* const* d_in, const int* in_sizes, int n_in,
                              void* d_out, int out_size, void* d_ws, size_t ws_size,
                              hipStream_t stream) {
    const float* x      = (const float*)d_in[0];
    const float* W_attn = (const float*)d_in[1];
    const float* b_attn = (const float*)d_in[2];
    const float* W_proj = (const float*)d_in[3];
    const float* b_proj = (const float*)d_in[4];
    float* out = (float*)d_out;

    __hip_bfloat16* wsb = reinterpret_cast<__hip_bfloat16*>(d_ws);
    __hip_bfloat16* xb  = wsb;                              // 8192*1024
    __hip_bfloat16* WaT = xb + (size_t)8192 * 1024;         // 3072*1024
    __hip_bfloat16* WpT = WaT + (size_t)3072 * 1024;        // 1024*1024
    __hip_bfloat16* qd  = WpT + (size_t)1024 * 1024;        // 64*2048*64
    __hip_bfloat16* kd  = qd + (size_t)64 * 2048 * 64;
    __hip_bfloat16* vtd = kd + (size_t)64 * 2048 * 64;
    __hip_bfloat16* ya  = vtd + (size_t)64 * 2048 * 64;     // 8192*1024

    cast_x_kernel<<<4096, 256, 0, stream>>>(x, xb, 8192 * 1024);
    transpose_cast_kernel<<<dim3(96, 32), 256, 0, stream>>>(W_attn, WaT, 1024, 3072);
    transpose_cast_kernel<<<dim3(32, 32), 256, 0, stream>>>(W_proj, WpT, 1024, 1024);
    gemm_qkv_kernel<<<dim3(128, 48), 256, 0, stream>>>(xb, WaT, b_attn, qd, kd, vtd);
    attn_kernel<<<dim3(32, 64), 256, 0, stream>>>(qd, kd, vtd, ya);
    gemm_proj_kernel<<<dim3(128, 16), 256, 0, stream>>>(ya, WpT, b_proj, out);
}

// Round 2
// 822.625 us; speedup vs baseline: 1.2612x; 1.2612x over previous
//
#include <hip/hip_runtime.h>
#include <hip/hip_bf16.h>
#include <math.h>

// Problem: B=4, T=2048, C=1024, H=16, D=64
// out = proj( attention( x @ W_attn + b_attn ) ) + b_proj

typedef __bf16 bf16x8 __attribute__((ext_vector_type(8)));
typedef float f32x4 __attribute__((ext_vector_type(4)));

__device__ __forceinline__ f32x4 mfma16(bf16x8 a, bf16x8 b, f32x4 c) {
    return __builtin_amdgcn_mfma_f32_16x16x32_bf16(a, b, c, 0, 0, 0);
}

// ---- cast x (fp32) -> bf16, 8 elems/thread ----
__global__ __launch_bounds__(256) void cast_x_kernel(const float* __restrict__ in,
                                                     __hip_bfloat16* __restrict__ out, int n) {
    int i = (blockIdx.x * 256 + threadIdx.x) * 8;
    if (i >= n) return;
    union { __hip_bfloat16 h[8]; uint4 v; } tmp;
#pragma unroll
    for (int j = 0; j < 8; ++j) tmp.h[j] = __float2bfloat16(in[i + j]);
    *reinterpret_cast<uint4*>(out + i) = tmp.v;
}

// ---- transpose+cast: in[R][Cc] fp32 -> out[Cc][R] bf16 ----
__global__ __launch_bounds__(256) void transpose_cast_kernel(const float* __restrict__ in,
                                                             __hip_bfloat16* __restrict__ out,
                                                             int R, int Cc) {
    __shared__ float tile[32][33];
    int c0 = blockIdx.x * 32, r0 = blockIdx.y * 32;
    int tx = threadIdx.x & 31, ty = threadIdx.x >> 5;  // ty 0..7
#pragma unroll
    for (int i = 0; i < 4; ++i) {
        int r = r0 + ty + i * 8;
        tile[ty + i * 8][tx] = in[(size_t)r * Cc + c0 + tx];
    }
    __syncthreads();
#pragma unroll
    for (int i = 0; i < 4; ++i) {
        int c = c0 + ty + i * 8;
        out[(size_t)c * R + r0 + tx] = __float2bfloat16(tile[tx][ty + i * 8]);
    }
}

// ---- QKV GEMM: A[8192,1024]bf16 x Bt[3072,1024]bf16 + bias ----
// q,k -> [B,H,T,D] bf16 ; v -> transposed [B,H,D,T] bf16
__global__ __launch_bounds__(256) void gemm_qkv_kernel(
    const __hip_bfloat16* __restrict__ A, const __hip_bfloat16* __restrict__ Bt,
    const float* __restrict__ bias,
    __hip_bfloat16* __restrict__ qd, __hip_bfloat16* __restrict__ kd,
    __hip_bfloat16* __restrict__ vtd) {
    const int K = 1024;
    int w = threadIdx.x >> 6, l = threadIdx.x & 63;
    int lr = l & 15, lh = l >> 4;
    int m0 = blockIdx.x * 64 + w * 16;
    int n0 = blockIdx.y * 64;
    f32x4 zero = {0.f, 0.f, 0.f, 0.f};
    f32x4 acc[4] = {zero, zero, zero, zero};
    const __hip_bfloat16* ap = A + (size_t)(m0 + lr) * K + lh * 8;
    const __hip_bfloat16* bp = Bt + (size_t)(n0 + lr) * K + lh * 8;
    for (int k0 = 0; k0 < K; k0 += 32) {
        bf16x8 a = *reinterpret_cast<const bf16x8*>(ap + k0);
#pragma unroll
        for (int nt = 0; nt < 4; ++nt) {
            bf16x8 b = *reinterpret_cast<const bf16x8*>(bp + (size_t)nt * 16 * K + k0);
            acc[nt] = mfma16(a, b, acc[nt]);
        }
    }
#pragma unroll
    for (int nt = 0; nt < 4; ++nt) {
        int n = n0 + nt * 16 + lr;
        float bv = bias[n];
#pragma unroll
        for (int r = 0; r < 4; ++r) {
            int m = m0 + 4 * lh + r;
            int bb = m >> 11, t = m & 2047;
            __hip_bfloat16 hv = __float2bfloat16(acc[nt][r] + bv);
            if (n < 1024) {
                int hh = n >> 6, dd = n & 63;
                qd[(((size_t)bb * 16 + hh) * 2048 + t) * 64 + dd] = hv;
            } else if (n < 2048) {
                int c = n - 1024, hh = c >> 6, dd = c & 63;
                kd[(((size_t)bb * 16 + hh) * 2048 + t) * 64 + dd] = hv;
            } else {
                int c = n - 2048, hh = c >> 6, dd = c & 63;
                vtd[(((size_t)bb * 16 + hh) * 64 + dd) * 2048 + t] = hv;
            }
        }
    }
}

// ---- causal flash attention v2 ----
// Per wave: 32 q rows (2 x 16-row frags), KVBLK=64.
// q,k: [BH, T, D] bf16 ; vt: [BH, D, T] bf16 ; y: [B, T, C] bf16
__global__ __launch_bounds__(256) void attn_kernel(
    const __hip_bfloat16* __restrict__ q, const __hip_bfloat16* __restrict__ k,
    const __hip_bfloat16* __restrict__ vt, __hip_bfloat16* __restrict__ y) {
    const int T = 2048, D = 64, C = 1024;
    int bh = blockIdx.y;
    int b = bh >> 4, h = bh & 15;
    int w = threadIdx.x >> 6, l = threadIdx.x & 63;
    int lr = l & 15, lh = l >> 4;
    int q0 = blockIdx.x * 128 + w * 32;
    // per-wave P tile: [wave][frag][16 rows][72] (stride 72 keeps b128 reads aligned)
    __shared__ __hip_bfloat16 P[4][2][16][72];

    // Q fragments: qa[f][dd]  (f: q-row frag, dd: 32-wide d chunk)
    bf16x8 qa[2][2];
#pragma unroll
    for (int f = 0; f < 2; ++f)
#pragma unroll
        for (int dd = 0; dd < 2; ++dd)
            qa[f][dd] = *reinterpret_cast<const bf16x8*>(
                q + ((size_t)bh * T + q0 + 16 * f + lr) * D + 32 * dd + 8 * lh);

    f32x4 zero = {0.f, 0.f, 0.f, 0.f};
    f32x4 o[2][4];
    float mrun[2][4], lrun[2][4];
#pragma unroll
    for (int f = 0; f < 2; ++f)
#pragma unroll
        for (int r = 0; r < 4; ++r) {
            o[f][r] = zero;  // reuse r as dt index below; init all 4
            mrun[f][r] = -INFINITY;
            lrun[f][r] = 0.f;
        }

    const int qmax = q0 + 31;
    for (int kv0 = 0; kv0 <= qmax; kv0 += 64) {
        // K fragments: kb[ct][dd] — shared by both q-frags
        bf16x8 kb[4][2];
#pragma unroll
        for (int ct = 0; ct < 4; ++ct)
#pragma unroll
            for (int dd = 0; dd < 2; ++dd)
                kb[ct][dd] = *reinterpret_cast<const bf16x8*>(
                    k + ((size_t)bh * T + kv0 + 16 * ct + lr) * D + 32 * dd + 8 * lh);

        // QK^T: s[f][ct] covers S[q0+16f .. +16) x [kv0+16ct .. +16)
        f32x4 s[2][4];
#pragma unroll
        for (int f = 0; f < 2; ++f)
#pragma unroll
            for (int ct = 0; ct < 4; ++ct) {
                f32x4 acc = zero;
                acc = mfma16(qa[f][0], kb[ct][0], acc);
                acc = mfma16(qa[f][1], kb[ct][1], acc);
                s[f][ct] = acc;
            }

        // V fragments early (latency hidden under softmax VALU)
        bf16x8 vb[4][2];
#pragma unroll
        for (int dt = 0; dt < 4; ++dt)
#pragma unroll
            for (int kk = 0; kk < 2; ++kk)
                vb[dt][kk] = *reinterpret_cast<const bf16x8*>(
                    vt + ((size_t)bh * D + 16 * dt + lr) * T + kv0 + 32 * kk + 8 * lh);

        // mask (diagonal tiles only) + scale
#pragma unroll
        for (int f = 0; f < 2; ++f) {
            if (kv0 + 63 > q0 + 16 * f) {
#pragma unroll
                for (int ct = 0; ct < 4; ++ct)
#pragma unroll
                    for (int r = 0; r < 4; ++r) {
                        int qq = q0 + 16 * f + 4 * lh + r;
                        int kc = kv0 + 16 * ct + lr;
                        s[f][ct][r] = (kc <= qq) ? s[f][ct][r] * 0.125f : -INFINITY;
                    }
            } else {
#pragma unroll
                for (int ct = 0; ct < 4; ++ct)
#pragma unroll
                    for (int r = 0; r < 4; ++r) s[f][ct][r] *= 0.125f;
            }
        }

        // online softmax per frag
#pragma unroll
        for (int f = 0; f < 2; ++f) {
            float mx[4];
#pragma unroll
            for (int r = 0; r < 4; ++r)
                mx[r] = fmaxf(fmaxf(s[f][0][r], s[f][1][r]), fmaxf(s[f][2][r], s[f][3][r]));
#pragma unroll
            for (int d = 1; d < 16; d <<= 1)
#pragma unroll
                for (int r = 0; r < 4; ++r) mx[r] = fmaxf(mx[r], __shfl_xor(mx[r], d, 16));

            float al[4];
#pragma unroll
            for (int r = 0; r < 4; ++r) {
                float mnew = fmaxf(mrun[f][r], mx[r]);
                al[r] = __expf(mrun[f][r] - mnew);
                mrun[f][r] = mnew;
            }
#pragma unroll
            for (int ct = 0; ct < 4; ++ct)
#pragma unroll
                for (int r = 0; r < 4; ++r) s[f][ct][r] = __expf(s[f][ct][r] - mrun[f][r]);

            float ps[4];
#pragma unroll
            for (int r = 0; r < 4; ++r)
                ps[r] = (s[f][0][r] + s[f][1][r]) + (s[f][2][r] + s[f][3][r]);
#pragma unroll
            for (int d = 1; d < 16; d <<= 1)
#pragma unroll
                for (int r = 0; r < 4; ++r) ps[r] += __shfl_xor(ps[r], d, 16);
#pragma unroll
            for (int r = 0; r < 4; ++r) lrun[f][r] = lrun[f][r] * al[r] + ps[r];
#pragma unroll
            for (int dt = 0; dt < 4; ++dt)
#pragma unroll
                for (int r = 0; r < 4; ++r) o[f][dt][r] *= al[r];

            // stage P (wave-internal LDS, no barrier)
#pragma unroll
            for (int ct = 0; ct < 4; ++ct)
#pragma unroll
                for (int r = 0; r < 4; ++r)
                    P[w][f][4 * lh + r][16 * ct + lr] = __float2bfloat16(s[f][ct][r]);
        }

        // PV
#pragma unroll
        for (int f = 0; f < 2; ++f) {
            bf16x8 pa0 = *reinterpret_cast<const bf16x8*>(&P[w][f][lr][8 * lh]);
            bf16x8 pa1 = *reinterpret_cast<const bf16x8*>(&P[w][f][lr][32 + 8 * lh]);
#pragma unroll
            for (int dt = 0; dt < 4; ++dt) {
                o[f][dt] = mfma16(pa0, vb[dt][0], o[f][dt]);
                o[f][dt] = mfma16(pa1, vb[dt][1], o[f][dt]);
            }
        }
    }

    // epilogue
#pragma unroll
    for (int f = 0; f < 2; ++f) {
        float inv[4];
#pragma unroll
        for (int r = 0; r < 4; ++r) inv[r] = 1.0f / lrun[f][r];
#pragma unroll
        for (int dt = 0; dt < 4; ++dt)
#pragma unroll
            for (int r = 0; r < 4; ++r) {
                int qq = q0 + 16 * f + 4 * lh + r;
                y[((size_t)b * T + qq) * C + h * 64 + dt * 16 + lr] =
                    __float2bfloat16(o[f][dt][r] * inv[r]);
            }
    }
}

// ---- proj GEMM: A[8192,1024]bf16 x Bt[1024,1024]bf16 + bias -> fp32 out ----
__global__ __launch_bounds__(256) void gemm_proj_kernel(
    const __hip_bfloat16* __restrict__ A, const __hip_bfloat16* __restrict__ Bt,
    const float* __restrict__ bias, float* __restrict__ out) {
    const int K = 1024, N = 1024;
    int w = threadIdx.x >> 6, l = threadIdx.x & 63;
    int lr = l & 15, lh = l >> 4;
    int m0 = blockIdx.x * 64 + w * 16;
    int n0 = blockIdx.y * 64;
    f32x4 zero = {0.f, 0.f, 0.f, 0.f};
    f32x4 acc[4] = {zero, zero, zero, zero};
    const __hip_bfloat16* ap = A + (size_t)(m0 + lr) * K + lh * 8;
    const __hip_bfloat16* bp = Bt + (size_t)(n0 + lr) * K + lh * 8;
    for (int k0 = 0; k0 < K; k0 += 32) {
        bf16x8 a = *reinterpret_cast<const bf16x8*>(ap + k0);
#pragma unroll
        for (int nt = 0; nt < 4; ++nt) {
            bf16x8 b = *reinterpret_cast<const bf16x8*>(bp + (size_t)nt * 16 * K + k0);
            acc[nt] = mfma16(a, b, acc[nt]);
        }
    }
#pragma unroll
    for (int nt = 0; nt < 4; ++nt) {
        int n = n0 + nt * 16 + lr;
        float bv = bias[n];
#pragma unroll
        for (int r = 0; r < 4; ++r) {
            int m = m0 + 4 * lh + r;
            out[(size_t)m * N + n] = acc[nt][r] + bv;
        }
    }
}

extern "C" void kernel_launch(void* const* d_in, const int* in_sizes, int n_in,
                              void* d_out, int out_size, void* d_ws, size_t ws_size,
                              hipStream_t stream) {
    const float* x      = (const float*)d_in[0];
    const float* W_attn = (const float*)d_in[1];
    const float* b_attn = (const float*)d_in[2];
    const float* W_proj = (const float*)d_in[3];
    const float* b_proj = (const float*)d_in[4];
    float* out = (float*)d_out;

    __hip_bfloat16* wsb = reinterpret_cast<__hip_bfloat16*>(d_ws);
    __hip_bfloat16* xb  = wsb;                              // 8192*1024
    __hip_bfloat16* WaT = xb + (size_t)8192 * 1024;         // 3072*1024
    __hip_bfloat16* WpT = WaT + (size_t)3072 * 1024;        // 1024*1024
    __hip_bfloat16* qd  = WpT + (size_t)1024 * 1024;        // 64*2048*64
    __hip_bfloat16* kd  = qd + (size_t)64 * 2048 * 64;
    __hip_bfloat16* vtd = kd + (size_t)64 * 2048 * 64;
    __hip_bfloat16* ya  = vtd + (size_t)64 * 2048 * 64;     // 8192*1024

    cast_x_kernel<<<4096, 256, 0, stream>>>(x, xb, 8192 * 1024);
    transpose_cast_kernel<<<dim3(96, 32), 256, 0, stream>>>(W_attn, WaT, 1024, 3072);
    transpose_cast_kernel<<<dim3(32, 32), 256, 0, stream>>>(W_proj, WpT, 1024, 1024);
    gemm_qkv_kernel<<<dim3(128, 48), 256, 0, stream>>>(xb, WaT, b_attn, qd, kd, vtd);
    attn_kernel<<<dim3(16, 64), 256, 0, stream>>>(qd, kd, vtd, ya);
    gemm_proj_kernel<<<dim3(128, 16), 256, 0, stream>>>(ya, WpT, b_proj, out);
}

// Round 3
// 335.564 us; speedup vs baseline: 3.0917x; 2.4515x over previous
//
#include <hip/hip_runtime.h>
#include <hip/hip_bf16.h>
#include <math.h>

// Problem: B=4, T=2048, C=1024, H=16, D=64
// out = proj( attention( x @ W_attn + b_attn ) ) + b_proj

typedef __bf16 bf16x8 __attribute__((ext_vector_type(8)));
typedef float f32x4 __attribute__((ext_vector_type(4)));

__device__ __forceinline__ f32x4 mfma16(bf16x8 a, bf16x8 b, f32x4 c) {
    return __builtin_amdgcn_mfma_f32_16x16x32_bf16(a, b, c, 0, 0, 0);
}

#define GLOBAL_AS __attribute__((address_space(1)))
#define LDS_AS __attribute__((address_space(3)))

// async 16B/lane global->LDS (dest is wave-uniform base + lane*16)
__device__ __forceinline__ void async_copy16(const __hip_bfloat16* g, __hip_bfloat16* l) {
    __builtin_amdgcn_global_load_lds((const GLOBAL_AS uint32_t*)g, (LDS_AS uint32_t*)l, 16, 0, 0);
}

// ---- cast x (fp32) -> bf16, 8 elems/thread ----
__global__ __launch_bounds__(256) void cast_x_kernel(const float* __restrict__ in,
                                                     __hip_bfloat16* __restrict__ out, int n) {
    int i = (blockIdx.x * 256 + threadIdx.x) * 8;
    if (i >= n) return;
    union { __hip_bfloat16 h[8]; uint4 v; } tmp;
#pragma unroll
    for (int j = 0; j < 8; ++j) tmp.h[j] = __float2bfloat16(in[i + j]);
    *reinterpret_cast<uint4*>(out + i) = tmp.v;
}

// ---- transpose+cast: in[R][Cc] fp32 -> out[Cc][R] bf16 ----
__global__ __launch_bounds__(256) void transpose_cast_kernel(const float* __restrict__ in,
                                                             __hip_bfloat16* __restrict__ out,
                                                             int R, int Cc) {
    __shared__ float tile[32][33];
    int c0 = blockIdx.x * 32, r0 = blockIdx.y * 32;
    int tx = threadIdx.x & 31, ty = threadIdx.x >> 5;  // ty 0..7
#pragma unroll
    for (int i = 0; i < 4; ++i) {
        int r = r0 + ty + i * 8;
        tile[ty + i * 8][tx] = in[(size_t)r * Cc + c0 + tx];
    }
    __syncthreads();
#pragma unroll
    for (int i = 0; i < 4; ++i) {
        int c = c0 + ty + i * 8;
        out[(size_t)c * R + r0 + tx] = __float2bfloat16(tile[tx][ty + i * 8]);
    }
}

// ================= m97-style 128x128 GEMM core =================
// A [M,K] bf16 row-major, Bt [N,K] bf16 row-major (i.e. B^T). BK=32.
// 256 thr = 4 waves (2x2), wave computes 64x64 = 4x4 frags of 16x16.
// acc[mf][nf]: C row = m0+wr*64+mf*16+4*lh+r, col = n0+wc*64+nf*16+lr.

#define GEMM128_BODY(A_, Bt_, K_)                                                       \
    __shared__ __hip_bfloat16 As[128 * 32];                                             \
    __shared__ __hip_bfloat16 Bs[128 * 32];                                             \
    const int tid = threadIdx.x;                                                        \
    const int w = tid >> 6;                                                             \
    const int lr = tid & 15, lh = (tid & 63) >> 4;                                      \
    const int wr = w >> 1, wc = w & 1;                                                  \
    f32x4 zero = {0.f, 0.f, 0.f, 0.f};                                                  \
    f32x4 acc[4][4];                                                                    \
    _Pragma("unroll") for (int i = 0; i < 4; ++i)                                       \
        _Pragma("unroll") for (int j = 0; j < 4; ++j) acc[i][j] = zero;                 \
    for (int k0 = 0; k0 < (K_); k0 += 32) {                                             \
        _Pragma("unroll") for (int i = 0; i < 2; ++i) {                                 \
            int t = i * 256 + tid;                                                      \
            async_copy16((A_) + (size_t)(m0 + (t >> 2)) * (K_) + k0 + (t & 3) * 8,      \
                         As + (size_t)(i * 256 + w * 64) * 8);                          \
            async_copy16((Bt_) + (size_t)(n0 + (t >> 2)) * (K_) + k0 + (t & 3) * 8,     \
                         Bs + (size_t)(i * 256 + w * 64) * 8);                          \
        }                                                                               \
        __syncthreads();                                                                \
        bf16x8 af[4], bf[4];                                                            \
        _Pragma("unroll") for (int mf = 0; mf < 4; ++mf)                                \
            af[mf] = *reinterpret_cast<const bf16x8*>(                                  \
                &As[(wr * 64 + mf * 16 + lr) * 32 + lh * 8]);                           \
        _Pragma("unroll") for (int nf = 0; nf < 4; ++nf)                                \
            bf[nf] = *reinterpret_cast<const bf16x8*>(                                  \
                &Bs[(wc * 64 + nf * 16 + lr) * 32 + lh * 8]);                           \
        _Pragma("unroll") for (int mf = 0; mf < 4; ++mf)                                \
            _Pragma("unroll") for (int nf = 0; nf < 4; ++nf)                            \
                acc[mf][nf] = mfma16(af[mf], bf[nf], acc[mf][nf]);                      \
        __syncthreads();                                                                \
    }

// ---- QKV GEMM: A[8192,1024] x Bt[3072,1024] + bias ----
// q,k -> [B,H,T,D] bf16 ; v -> transposed [B,H,D,T] bf16
__global__ __launch_bounds__(256) void gemm_qkv_kernel(
    const __hip_bfloat16* __restrict__ A, const __hip_bfloat16* __restrict__ Bt,
    const float* __restrict__ bias,
    __hip_bfloat16* __restrict__ qd, __hip_bfloat16* __restrict__ kd,
    __hip_bfloat16* __restrict__ vtd) {
    const int K = 1024;
    const int m0 = blockIdx.x * 128;
    const int n0 = blockIdx.y * 128;
    GEMM128_BODY(A, Bt, K)

    const int region = n0 >> 10;  // 0:q 1:k 2:v (block-uniform, n-tile is 1024-aligned)
#pragma unroll
    for (int mf = 0; mf < 4; ++mf) {
#pragma unroll
        for (int nf = 0; nf < 4; ++nf) {
            int n = n0 + wc * 64 + nf * 16 + lr;
            float bv = bias[n];
            int mbase = m0 + wr * 64 + mf * 16 + 4 * lh;
            int bb = mbase >> 11;
            int t = mbase & 2047;
            int c = n & 1023, hh = c >> 6, dd = c & 63;
            if (region == 2) {
                union { __hip_bfloat16 h[4]; uint2 v; } pk;
#pragma unroll
                for (int r = 0; r < 4; ++r) pk.h[r] = __float2bfloat16(acc[mf][nf][r] + bv);
                *reinterpret_cast<uint2*>(
                    &vtd[(((size_t)bb * 16 + hh) * 64 + dd) * 2048 + t]) = pk.v;
            } else {
                __hip_bfloat16* dst = (region == 0) ? qd : kd;
#pragma unroll
                for (int r = 0; r < 4; ++r)
                    dst[(((size_t)bb * 16 + hh) * 2048 + t + r) * 64 + dd] =
                        __float2bfloat16(acc[mf][nf][r] + bv);
            }
        }
    }
}

// ---- proj GEMM: A[8192,1024] x Bt[1024,1024] + bias -> fp32 out ----
__global__ __launch_bounds__(256) void gemm_proj_kernel(
    const __hip_bfloat16* __restrict__ A, const __hip_bfloat16* __restrict__ Bt,
    const float* __restrict__ bias, float* __restrict__ out) {
    const int K = 1024, N = 1024;
    const int m0 = blockIdx.x * 128;
    const int n0 = blockIdx.y * 128;
    GEMM128_BODY(A, Bt, K)

#pragma unroll
    for (int nf = 0; nf < 4; ++nf) {
        int n = n0 + wc * 64 + nf * 16 + lr;
        float bv = bias[n];
#pragma unroll
        for (int mf = 0; mf < 4; ++mf) {
            int mbase = m0 + wr * 64 + mf * 16 + 4 * lh;
#pragma unroll
            for (int r = 0; r < 4; ++r)
                out[(size_t)(mbase + r) * N + n] = acc[mf][nf][r] + bv;
        }
    }
}

// ---- causal flash attention v2 (unchanged from R1) ----
__global__ __launch_bounds__(256) void attn_kernel(
    const __hip_bfloat16* __restrict__ q, const __hip_bfloat16* __restrict__ k,
    const __hip_bfloat16* __restrict__ vt, __hip_bfloat16* __restrict__ y) {
    const int T = 2048, D = 64, C = 1024;
    int bh = blockIdx.y;
    int b = bh >> 4, h = bh & 15;
    int w = threadIdx.x >> 6, l = threadIdx.x & 63;
    int lr = l & 15, lh = l >> 4;
    int q0 = blockIdx.x * 128 + w * 32;
    __shared__ __hip_bfloat16 P[4][2][16][72];

    bf16x8 qa[2][2];
#pragma unroll
    for (int f = 0; f < 2; ++f)
#pragma unroll
        for (int dd = 0; dd < 2; ++dd)
            qa[f][dd] = *reinterpret_cast<const bf16x8*>(
                q + ((size_t)bh * T + q0 + 16 * f + lr) * D + 32 * dd + 8 * lh);

    f32x4 zero = {0.f, 0.f, 0.f, 0.f};
    f32x4 o[2][4];
    float mrun[2][4], lrun[2][4];
#pragma unroll
    for (int f = 0; f < 2; ++f)
#pragma unroll
        for (int r = 0; r < 4; ++r) {
            o[f][r] = zero;
            mrun[f][r] = -INFINITY;
            lrun[f][r] = 0.f;
        }

    const int qmax = q0 + 31;
    for (int kv0 = 0; kv0 <= qmax; kv0 += 64) {
        bf16x8 kb[4][2];
#pragma unroll
        for (int ct = 0; ct < 4; ++ct)
#pragma unroll
            for (int dd = 0; dd < 2; ++dd)
                kb[ct][dd] = *reinterpret_cast<const bf16x8*>(
                    k + ((size_t)bh * T + kv0 + 16 * ct + lr) * D + 32 * dd + 8 * lh);

        f32x4 s[2][4];
#pragma unroll
        for (int f = 0; f < 2; ++f)
#pragma unroll
            for (int ct = 0; ct < 4; ++ct) {
                f32x4 acc = zero;
                acc = mfma16(qa[f][0], kb[ct][0], acc);
                acc = mfma16(qa[f][1], kb[ct][1], acc);
                s[f][ct] = acc;
            }

        bf16x8 vb[4][2];
#pragma unroll
        for (int dt = 0; dt < 4; ++dt)
#pragma unroll
            for (int kk = 0; kk < 2; ++kk)
                vb[dt][kk] = *reinterpret_cast<const bf16x8*>(
                    vt + ((size_t)bh * D + 16 * dt + lr) * T + kv0 + 32 * kk + 8 * lh);

#pragma unroll
        for (int f = 0; f < 2; ++f) {
            if (kv0 + 63 > q0 + 16 * f) {
#pragma unroll
                for (int ct = 0; ct < 4; ++ct)
#pragma unroll
                    for (int r = 0; r < 4; ++r) {
                        int qq = q0 + 16 * f + 4 * lh + r;
                        int kc = kv0 + 16 * ct + lr;
                        s[f][ct][r] = (kc <= qq) ? s[f][ct][r] * 0.125f : -INFINITY;
                    }
            } else {
#pragma unroll
                for (int ct = 0; ct < 4; ++ct)
#pragma unroll
                    for (int r = 0; r < 4; ++r) s[f][ct][r] *= 0.125f;
            }
        }

#pragma unroll
        for (int f = 0; f < 2; ++f) {
            float mx[4];
#pragma unroll
            for (int r = 0; r < 4; ++r)
                mx[r] = fmaxf(fmaxf(s[f][0][r], s[f][1][r]), fmaxf(s[f][2][r], s[f][3][r]));
#pragma unroll
            for (int d = 1; d < 16; d <<= 1)
#pragma unroll
                for (int r = 0; r < 4; ++r) mx[r] = fmaxf(mx[r], __shfl_xor(mx[r], d, 16));

            float al[4];
#pragma unroll
            for (int r = 0; r < 4; ++r) {
                float mnew = fmaxf(mrun[f][r], mx[r]);
                al[r] = __expf(mrun[f][r] - mnew);
                mrun[f][r] = mnew;
            }
#pragma unroll
            for (int ct = 0; ct < 4; ++ct)
#pragma unroll
                for (int r = 0; r < 4; ++r) s[f][ct][r] = __expf(s[f][ct][r] - mrun[f][r]);

            float ps[4];
#pragma unroll
            for (int r = 0; r < 4; ++r)
                ps[r] = (s[f][0][r] + s[f][1][r]) + (s[f][2][r] + s[f][3][r]);
#pragma unroll
            for (int d = 1; d < 16; d <<= 1)
#pragma unroll
                for (int r = 0; r < 4; ++r) ps[r] += __shfl_xor(ps[r], d, 16);
#pragma unroll
            for (int r = 0; r < 4; ++r) lrun[f][r] = lrun[f][r] * al[r] + ps[r];
#pragma unroll
            for (int dt = 0; dt < 4; ++dt)
#pragma unroll
                for (int r = 0; r < 4; ++r) o[f][dt][r] *= al[r];

#pragma unroll
            for (int ct = 0; ct < 4; ++ct)
#pragma unroll
                for (int r = 0; r < 4; ++r)
                    P[w][f][4 * lh + r][16 * ct + lr] = __float2bfloat16(s[f][ct][r]);
        }

#pragma unroll
        for (int f = 0; f < 2; ++f) {
            bf16x8 pa0 = *reinterpret_cast<const bf16x8*>(&P[w][f][lr][8 * lh]);
            bf16x8 pa1 = *reinterpret_cast<const bf16x8*>(&P[w][f][lr][32 + 8 * lh]);
#pragma unroll
            for (int dt = 0; dt < 4; ++dt) {
                o[f][dt] = mfma16(pa0, vb[dt][0], o[f][dt]);
                o[f][dt] = mfma16(pa1, vb[dt][1], o[f][dt]);
            }
        }
    }

#pragma unroll
    for (int f = 0; f < 2; ++f) {
        float inv[4];
#pragma unroll
        for (int r = 0; r < 4; ++r) inv[r] = 1.0f / lrun[f][r];
#pragma unroll
        for (int dt = 0; dt < 4; ++dt)
#pragma unroll
            for (int r = 0; r < 4; ++r) {
                int qq = q0 + 16 * f + 4 * lh + r;
                y[((size_t)b * T + qq) * C + h * 64 + dt * 16 + lr] =
                    __float2bfloat16(o[f][dt][r] * inv[r]);
            }
    }
}

extern "C" void kernel_launch(void* const* d_in, const int* in_sizes, int n_in,
                              void* d_out, int out_size, void* d_ws, size_t ws_size,
                              hipStream_t stream) {
    const float* x      = (const float*)d_in[0];
    const float* W_attn = (const float*)d_in[1];
    const float* b_attn = (const float*)d_in[2];
    const float* W_proj = (const float*)d_in[3];
    const float* b_proj = (const float*)d_in[4];
    float* out = (float*)d_out;

    __hip_bfloat16* wsb = reinterpret_cast<__hip_bfloat16*>(d_ws);
    __hip_bfloat16* xb  = wsb;                              // 8192*1024
    __hip_bfloat16* WaT = xb + (size_t)8192 * 1024;         // 3072*1024
    __hip_bfloat16* WpT = WaT + (size_t)3072 * 1024;        // 1024*1024
    __hip_bfloat16* qd  = WpT + (size_t)1024 * 1024;        // 64*2048*64
    __hip_bfloat16* kd  = qd + (size_t)64 * 2048 * 64;
    __hip_bfloat16* vtd = kd + (size_t)64 * 2048 * 64;
    __hip_bfloat16* ya  = vtd + (size_t)64 * 2048 * 64;     // 8192*1024

    cast_x_kernel<<<4096, 256, 0, stream>>>(x, xb, 8192 * 1024);
    transpose_cast_kernel<<<dim3(96, 32), 256, 0, stream>>>(W_attn, WaT, 1024, 3072);
    transpose_cast_kernel<<<dim3(32, 32), 256, 0, stream>>>(W_proj, WpT, 1024, 1024);
    gemm_qkv_kernel<<<dim3(64, 24), 256, 0, stream>>>(xb, WaT, b_attn, qd, kd, vtd);
    attn_kernel<<<dim3(16, 64), 256, 0, stream>>>(qd, kd, vtd, ya);
    gemm_proj_kernel<<<dim3(64, 8), 256, 0, stream>>>(ya, WpT, b_proj, out);
}

// Round 4
// 230.423 us; speedup vs baseline: 4.5024x; 1.4563x over previous
//
#include <hip/hip_runtime.h>
#include <hip/hip_bf16.h>
#include <math.h>

// Problem: B=4, T=2048, C=1024, H=16, D=64
// out = proj( attention( x @ W_attn + b_attn ) ) + b_proj

typedef __bf16 bf16x8 __attribute__((ext_vector_type(8)));
typedef float f32x4 __attribute__((ext_vector_type(4)));

__device__ __forceinline__ f32x4 mfma16(bf16x8 a, bf16x8 b, f32x4 c) {
    return __builtin_amdgcn_mfma_f32_16x16x32_bf16(a, b, c, 0, 0, 0);
}

#define GLOBAL_AS __attribute__((address_space(1)))
#define LDS_AS __attribute__((address_space(3)))

// async 16B/lane global->LDS (dest is wave-uniform base + lane*16)
__device__ __forceinline__ void async_copy16(const __hip_bfloat16* g, __hip_bfloat16* l) {
    __builtin_amdgcn_global_load_lds((const GLOBAL_AS uint32_t*)g, (LDS_AS uint32_t*)l, 16, 0, 0);
}

// ---- cast x (fp32) -> bf16, 8 elems/thread ----
__global__ __launch_bounds__(256) void cast_x_kernel(const float* __restrict__ in,
                                                     __hip_bfloat16* __restrict__ out, int n) {
    int i = (blockIdx.x * 256 + threadIdx.x) * 8;
    if (i >= n) return;
    union { __hip_bfloat16 h[8]; uint4 v; } tmp;
#pragma unroll
    for (int j = 0; j < 8; ++j) tmp.h[j] = __float2bfloat16(in[i + j]);
    *reinterpret_cast<uint4*>(out + i) = tmp.v;
}

// ---- transpose+cast: in[R][Cc] fp32 -> out[Cc][R] bf16 ----
__global__ __launch_bounds__(256) void transpose_cast_kernel(const float* __restrict__ in,
                                                             __hip_bfloat16* __restrict__ out,
                                                             int R, int Cc) {
    __shared__ float tile[32][33];
    int c0 = blockIdx.x * 32, r0 = blockIdx.y * 32;
    int tx = threadIdx.x & 31, ty = threadIdx.x >> 5;  // ty 0..7
#pragma unroll
    for (int i = 0; i < 4; ++i) {
        int r = r0 + ty + i * 8;
        tile[ty + i * 8][tx] = in[(size_t)r * Cc + c0 + tx];
    }
    __syncthreads();
#pragma unroll
    for (int i = 0; i < 4; ++i) {
        int c = c0 + ty + i * 8;
        out[(size_t)c * R + r0 + tx] = __float2bfloat16(tile[tx][ty + i * 8]);
    }
}

// ================= m97-style 128x128 GEMM core =================
#define GEMM128_BODY(A_, Bt_, K_)                                                       \
    __shared__ __hip_bfloat16 As[128 * 32];                                             \
    __shared__ __hip_bfloat16 Bs[128 * 32];                                             \
    const int tid = threadIdx.x;                                                        \
    const int w = tid >> 6;                                                             \
    const int lr = tid & 15, lh = (tid & 63) >> 4;                                      \
    const int wr = w >> 1, wc = w & 1;                                                  \
    f32x4 zero = {0.f, 0.f, 0.f, 0.f};                                                  \
    f32x4 acc[4][4];                                                                    \
    _Pragma("unroll") for (int i = 0; i < 4; ++i)                                       \
        _Pragma("unroll") for (int j = 0; j < 4; ++j) acc[i][j] = zero;                 \
    for (int k0 = 0; k0 < (K_); k0 += 32) {                                             \
        _Pragma("unroll") for (int i = 0; i < 2; ++i) {                                 \
            int t = i * 256 + tid;                                                      \
            async_copy16((A_) + (size_t)(m0 + (t >> 2)) * (K_) + k0 + (t & 3) * 8,      \
                         As + (size_t)(i * 256 + w * 64) * 8);                          \
            async_copy16((Bt_) + (size_t)(n0 + (t >> 2)) * (K_) + k0 + (t & 3) * 8,     \
                         Bs + (size_t)(i * 256 + w * 64) * 8);                          \
        }                                                                               \
        __syncthreads();                                                                \
        bf16x8 af[4], bf[4];                                                            \
        _Pragma("unroll") for (int mf = 0; mf < 4; ++mf)                                \
            af[mf] = *reinterpret_cast<const bf16x8*>(                                  \
                &As[(wr * 64 + mf * 16 + lr) * 32 + lh * 8]);                           \
        _Pragma("unroll") for (int nf = 0; nf < 4; ++nf)                                \
            bf[nf] = *reinterpret_cast<const bf16x8*>(                                  \
                &Bs[(wc * 64 + nf * 16 + lr) * 32 + lh * 8]);                           \
        _Pragma("unroll") for (int mf = 0; mf < 4; ++mf)                                \
            _Pragma("unroll") for (int nf = 0; nf < 4; ++nf)                            \
                acc[mf][nf] = mfma16(af[mf], bf[nf], acc[mf][nf]);                      \
        __syncthreads();                                                                \
    }

// ---- QKV GEMM ----
__global__ __launch_bounds__(256) void gemm_qkv_kernel(
    const __hip_bfloat16* __restrict__ A, const __hip_bfloat16* __restrict__ Bt,
    const float* __restrict__ bias,
    __hip_bfloat16* __restrict__ qd, __hip_bfloat16* __restrict__ kd,
    __hip_bfloat16* __restrict__ vtd) {
    const int K = 1024;
    const int m0 = blockIdx.x * 128;
    const int n0 = blockIdx.y * 128;
    GEMM128_BODY(A, Bt, K)

    const int region = n0 >> 10;  // 0:q 1:k 2:v (block-uniform)
#pragma unroll
    for (int mf = 0; mf < 4; ++mf) {
#pragma unroll
        for (int nf = 0; nf < 4; ++nf) {
            int n = n0 + wc * 64 + nf * 16 + lr;
            float bv = bias[n];
            int mbase = m0 + wr * 64 + mf * 16 + 4 * lh;
            int bb = mbase >> 11;
            int t = mbase & 2047;
            int c = n & 1023, hh = c >> 6, dd = c & 63;
            if (region == 2) {
                union { __hip_bfloat16 h[4]; uint2 v; } pk;
#pragma unroll
                for (int r = 0; r < 4; ++r) pk.h[r] = __float2bfloat16(acc[mf][nf][r] + bv);
                *reinterpret_cast<uint2*>(
                    &vtd[(((size_t)bb * 16 + hh) * 64 + dd) * 2048 + t]) = pk.v;
            } else {
                __hip_bfloat16* dst = (region == 0) ? qd : kd;
#pragma unroll
                for (int r = 0; r < 4; ++r)
                    dst[(((size_t)bb * 16 + hh) * 2048 + t + r) * 64 + dd] =
                        __float2bfloat16(acc[mf][nf][r] + bv);
            }
        }
    }
}

// ---- proj GEMM ----
__global__ __launch_bounds__(256) void gemm_proj_kernel(
    const __hip_bfloat16* __restrict__ A, const __hip_bfloat16* __restrict__ Bt,
    const float* __restrict__ bias, float* __restrict__ out) {
    const int K = 1024, N = 1024;
    const int m0 = blockIdx.x * 128;
    const int n0 = blockIdx.y * 128;
    GEMM128_BODY(A, Bt, K)

#pragma unroll
    for (int nf = 0; nf < 4; ++nf) {
        int n = n0 + wc * 64 + nf * 16 + lr;
        float bv = bias[n];
#pragma unroll
        for (int mf = 0; mf < 4; ++mf) {
            int mbase = m0 + wr * 64 + mf * 16 + 4 * lh;
#pragma unroll
            for (int r = 0; r < 4; ++r)
                out[(size_t)(mbase + r) * N + n] = acc[mf][nf][r] + bv;
        }
    }
}

// ---- causal flash attention v3 ----
// Block: 128 q rows (4 waves x 32), K/V tiles (64 kv) staged in swizzled LDS.
// Balanced pairing: block x processes q-tiles x and 15-x.
// q,k: [BH, T, D] bf16 ; vt: [BH, D, T] bf16 ; y: [B, T, C] bf16
__global__ __launch_bounds__(256) void attn_kernel(
    const __hip_bfloat16* __restrict__ q, const __hip_bfloat16* __restrict__ k,
    const __hip_bfloat16* __restrict__ vt, __hip_bfloat16* __restrict__ y) {
    const int T = 2048, D = 64, C = 1024;
    const float SCL = 0.125f;
    int bh = blockIdx.y;
    int b = bh >> 4, h = bh & 15;
    int tid = threadIdx.x;
    int w = tid >> 6, l = tid & 63;
    int lr = l & 15, lh = l >> 4;

    __shared__ __hip_bfloat16 Ks[64 * 64];  // [kv][d], xor-swizzled rows
    __shared__ __hip_bfloat16 Vs[64 * 64];  // [d][kv], xor-swizzled rows
    __shared__ __hip_bfloat16 P[4][2][16][72];

    const __hip_bfloat16* kbh = k + (size_t)bh * T * D;
    const __hip_bfloat16* vbh = vt + (size_t)bh * D * T;

    // staging source-lane geometry (shared by K and V): slot = j*256+tid
    // row = slot>>3 ; src col byte = ((slot&7)*16) ^ ((row&7)<<4)
#pragma unroll
    for (int pp = 0; pp < 2; ++pp) {
        int qt = pp ? (15 - (int)blockIdx.x) : (int)blockIdx.x;
        int q0 = qt * 128 + w * 32;

        bf16x8 qa[2][2];
#pragma unroll
        for (int f = 0; f < 2; ++f)
#pragma unroll
            for (int dd = 0; dd < 2; ++dd)
                qa[f][dd] = *reinterpret_cast<const bf16x8*>(
                    q + ((size_t)bh * T + q0 + 16 * f + lr) * D + 32 * dd + 8 * lh);

        f32x4 zero = {0.f, 0.f, 0.f, 0.f};
        f32x4 o[2][4];
        float mrun[2][4], lrun[2][4];
#pragma unroll
        for (int f = 0; f < 2; ++f)
#pragma unroll
            for (int r = 0; r < 4; ++r) {
                o[f][r] = zero;
                mrun[f][r] = -INFINITY;
                lrun[f][r] = 0.f;
            }

        int ntile = 2 * qt + 2;
        for (int t = 0; t < ntile; ++t) {
            int kv0 = t * 64;
            // ---- stage K and V tiles (all waves participate) ----
#pragma unroll
            for (int j = 0; j < 2; ++j) {
                int slot = j * 256 + tid;
                int row = slot >> 3;
                int colb = ((slot & 7) * 16) ^ ((row & 7) << 4);
                async_copy16(kbh + (size_t)(kv0 + row) * 64 + (colb >> 1),
                             Ks + (size_t)(j * 256 + w * 64) * 8);
                async_copy16(vbh + (size_t)row * T + kv0 + (colb >> 1),
                             Vs + (size_t)(j * 256 + w * 64) * 8);
            }
            __syncthreads();

            if (kv0 <= q0 + 31) {  // wave-uniform activity
                // K frags from LDS (swizzled)
                bf16x8 kb[4][2];
#pragma unroll
                for (int ct = 0; ct < 4; ++ct)
#pragma unroll
                    for (int dd = 0; dd < 2; ++dd) {
                        int row = 16 * ct + lr;
                        int colb = (dd * 64 + lh * 16) ^ ((lr & 7) << 4);
                        kb[ct][dd] = *reinterpret_cast<const bf16x8*>(
                            reinterpret_cast<const char*>(Ks) + row * 128 + colb);
                    }

                f32x4 s[2][4];
#pragma unroll
                for (int f = 0; f < 2; ++f)
#pragma unroll
                    for (int ct = 0; ct < 4; ++ct) {
                        f32x4 acc = zero;
                        acc = mfma16(qa[f][0], kb[ct][0], acc);
                        acc = mfma16(qa[f][1], kb[ct][1], acc);
                        s[f][ct] = acc;
                    }

                // V frags from LDS (swizzled)
                bf16x8 vb[4][2];
#pragma unroll
                for (int dt = 0; dt < 4; ++dt)
#pragma unroll
                    for (int kk = 0; kk < 2; ++kk) {
                        int row = 16 * dt + lr;
                        int colb = (kk * 64 + lh * 16) ^ ((lr & 7) << 4);
                        vb[dt][kk] = *reinterpret_cast<const bf16x8*>(
                            reinterpret_cast<const char*>(Vs) + row * 128 + colb);
                    }

                // mask (raw scores; scale folded into exp)
#pragma unroll
                for (int f = 0; f < 2; ++f) {
                    if (kv0 + 63 > q0 + 16 * f) {
#pragma unroll
                        for (int ct = 0; ct < 4; ++ct)
#pragma unroll
                            for (int r = 0; r < 4; ++r) {
                                int qq = q0 + 16 * f + 4 * lh + r;
                                int kc = kv0 + 16 * ct + lr;
                                if (kc > qq) s[f][ct][r] = -INFINITY;
                            }
                    }
                }

#pragma unroll
                for (int f = 0; f < 2; ++f) {
                    float mx[4];
#pragma unroll
                    for (int r = 0; r < 4; ++r)
                        mx[r] = fmaxf(fmaxf(s[f][0][r], s[f][1][r]),
                                      fmaxf(s[f][2][r], s[f][3][r]));
#pragma unroll
                    for (int d = 1; d < 16; d <<= 1)
#pragma unroll
                        for (int r = 0; r < 4; ++r) mx[r] = fmaxf(mx[r], __shfl_xor(mx[r], d, 16));

                    float al[4];
#pragma unroll
                    for (int r = 0; r < 4; ++r) {
                        float mnew = fmaxf(mrun[f][r], mx[r]);
                        al[r] = __expf((mrun[f][r] - mnew) * SCL);
                        mrun[f][r] = mnew;
                    }
#pragma unroll
                    for (int ct = 0; ct < 4; ++ct)
#pragma unroll
                        for (int r = 0; r < 4; ++r)
                            s[f][ct][r] = __expf((s[f][ct][r] - mrun[f][r]) * SCL);

                    float ps[4];
#pragma unroll
                    for (int r = 0; r < 4; ++r)
                        ps[r] = (s[f][0][r] + s[f][1][r]) + (s[f][2][r] + s[f][3][r]);
#pragma unroll
                    for (int d = 1; d < 16; d <<= 1)
#pragma unroll
                        for (int r = 0; r < 4; ++r) ps[r] += __shfl_xor(ps[r], d, 16);
#pragma unroll
                    for (int r = 0; r < 4; ++r) lrun[f][r] = lrun[f][r] * al[r] + ps[r];
#pragma unroll
                    for (int dt = 0; dt < 4; ++dt)
#pragma unroll
                        for (int r = 0; r < 4; ++r) o[f][dt][r] *= al[r];

#pragma unroll
                    for (int ct = 0; ct < 4; ++ct)
#pragma unroll
                        for (int r = 0; r < 4; ++r)
                            P[w][f][4 * lh + r][16 * ct + lr] = __float2bfloat16(s[f][ct][r]);
                }

#pragma unroll
                for (int f = 0; f < 2; ++f) {
                    bf16x8 pa0 = *reinterpret_cast<const bf16x8*>(&P[w][f][lr][8 * lh]);
                    bf16x8 pa1 = *reinterpret_cast<const bf16x8*>(&P[w][f][lr][32 + 8 * lh]);
#pragma unroll
                    for (int dt = 0; dt < 4; ++dt) {
                        o[f][dt] = mfma16(pa0, vb[dt][0], o[f][dt]);
                        o[f][dt] = mfma16(pa1, vb[dt][1], o[f][dt]);
                    }
                }
            }
            __syncthreads();
        }

        // epilogue
#pragma unroll
        for (int f = 0; f < 2; ++f) {
            float inv[4];
#pragma unroll
            for (int r = 0; r < 4; ++r) inv[r] = 1.0f / lrun[f][r];
#pragma unroll
            for (int dt = 0; dt < 4; ++dt)
#pragma unroll
                for (int r = 0; r < 4; ++r) {
                    int qq = q0 + 16 * f + 4 * lh + r;
                    y[((size_t)b * T + qq) * C + h * 64 + dt * 16 + lr] =
                        __float2bfloat16(o[f][dt][r] * inv[r]);
                }
        }
    }
}

extern "C" void kernel_launch(void* const* d_in, const int* in_sizes, int n_in,
                              void* d_out, int out_size, void* d_ws, size_t ws_size,
                              hipStream_t stream) {
    const float* x      = (const float*)d_in[0];
    const float* W_attn = (const float*)d_in[1];
    const float* b_attn = (const float*)d_in[2];
    const float* W_proj = (const float*)d_in[3];
    const float* b_proj = (const float*)d_in[4];
    float* out = (float*)d_out;

    __hip_bfloat16* wsb = reinterpret_cast<__hip_bfloat16*>(d_ws);
    __hip_bfloat16* xb  = wsb;                              // 8192*1024
    __hip_bfloat16* WaT = xb + (size_t)8192 * 1024;         // 3072*1024
    __hip_bfloat16* WpT = WaT + (size_t)3072 * 1024;        // 1024*1024
    __hip_bfloat16* qd  = WpT + (size_t)1024 * 1024;        // 64*2048*64
    __hip_bfloat16* kd  = qd + (size_t)64 * 2048 * 64;
    __hip_bfloat16* vtd = kd + (size_t)64 * 2048 * 64;
    __hip_bfloat16* ya  = vtd + (size_t)64 * 2048 * 64;     // 8192*1024

    cast_x_kernel<<<4096, 256, 0, stream>>>(x, xb, 8192 * 1024);
    transpose_cast_kernel<<<dim3(96, 32), 256, 0, stream>>>(W_attn, WaT, 1024, 3072);
    transpose_cast_kernel<<<dim3(32, 32), 256, 0, stream>>>(W_proj, WpT, 1024, 1024);
    gemm_qkv_kernel<<<dim3(64, 24), 256, 0, stream>>>(xb, WaT, b_attn, qd, kd, vtd);
    attn_kernel<<<dim3(8, 64), 256, 0, stream>>>(qd, kd, vtd, ya);
    gemm_proj_kernel<<<dim3(64, 8), 256, 0, stream>>>(ya, WpT, b_proj, out);
}

// Round 5
// 219.440 us; speedup vs baseline: 4.7277x; 1.0500x over previous
//
#include <hip/hip_runtime.h>
#include <hip/hip_bf16.h>
#include <math.h>

// Problem: B=4, T=2048, C=1024, H=16, D=64
// out = proj( attention( x @ W_attn + b_attn ) ) + b_proj

typedef __bf16 bf16x8 __attribute__((ext_vector_type(8)));
typedef float f32x4 __attribute__((ext_vector_type(4)));

__device__ __forceinline__ f32x4 mfma16(bf16x8 a, bf16x8 b, f32x4 c) {
    return __builtin_amdgcn_mfma_f32_16x16x32_bf16(a, b, c, 0, 0, 0);
}

#define GLOBAL_AS __attribute__((address_space(1)))
#define LDS_AS __attribute__((address_space(3)))

// async 16B/lane global->LDS (dest is wave-uniform base + lane*16)
__device__ __forceinline__ void async_copy16(const __hip_bfloat16* g, __hip_bfloat16* l) {
    __builtin_amdgcn_global_load_lds((const GLOBAL_AS uint32_t*)g, (LDS_AS uint32_t*)l, 16, 0, 0);
}

// q is pre-scaled by 0.125*log2(e) so softmax exps are pure exp2
#define QSCL 0.18033688011112042f

// ---- cast x (fp32) -> bf16, 8 elems/thread ----
__global__ __launch_bounds__(256) void cast_x_kernel(const float* __restrict__ in,
                                                     __hip_bfloat16* __restrict__ out, int n) {
    int i = (blockIdx.x * 256 + threadIdx.x) * 8;
    if (i >= n) return;
    union { __hip_bfloat16 h[8]; uint4 v; } tmp;
#pragma unroll
    for (int j = 0; j < 8; ++j) tmp.h[j] = __float2bfloat16(in[i + j]);
    *reinterpret_cast<uint4*>(out + i) = tmp.v;
}

// ---- transpose+cast: in[R][Cc] fp32 -> out[Cc][R] bf16 ----
__global__ __launch_bounds__(256) void transpose_cast_kernel(const float* __restrict__ in,
                                                             __hip_bfloat16* __restrict__ out,
                                                             int R, int Cc) {
    __shared__ float tile[32][33];
    int c0 = blockIdx.x * 32, r0 = blockIdx.y * 32;
    int tx = threadIdx.x & 31, ty = threadIdx.x >> 5;  // ty 0..7
#pragma unroll
    for (int i = 0; i < 4; ++i) {
        int r = r0 + ty + i * 8;
        tile[ty + i * 8][tx] = in[(size_t)r * Cc + c0 + tx];
    }
    __syncthreads();
#pragma unroll
    for (int i = 0; i < 4; ++i) {
        int c = c0 + ty + i * 8;
        out[(size_t)c * R + r0 + tx] = __float2bfloat16(tile[tx][ty + i * 8]);
    }
}

// ================= m97-style 128x128 GEMM core =================
#define GEMM128_BODY(A_, Bt_, K_)                                                       \
    __shared__ __hip_bfloat16 As[128 * 32];                                             \
    __shared__ __hip_bfloat16 Bs[128 * 32];                                             \
    const int tid = threadIdx.x;                                                        \
    const int w = tid >> 6;                                                             \
    const int lr = tid & 15, lh = (tid & 63) >> 4;                                      \
    const int wr = w >> 1, wc = w & 1;                                                  \
    f32x4 zero = {0.f, 0.f, 0.f, 0.f};                                                  \
    f32x4 acc[4][4];                                                                    \
    _Pragma("unroll") for (int i = 0; i < 4; ++i)                                       \
        _Pragma("unroll") for (int j = 0; j < 4; ++j) acc[i][j] = zero;                 \
    for (int k0 = 0; k0 < (K_); k0 += 32) {                                             \
        _Pragma("unroll") for (int i = 0; i < 2; ++i) {                                 \
            int t = i * 256 + tid;                                                      \
            async_copy16((A_) + (size_t)(m0 + (t >> 2)) * (K_) + k0 + (t & 3) * 8,      \
                         As + (size_t)(i * 256 + w * 64) * 8);                          \
            async_copy16((Bt_) + (size_t)(n0 + (t >> 2)) * (K_) + k0 + (t & 3) * 8,     \
                         Bs + (size_t)(i * 256 + w * 64) * 8);                          \
        }                                                                               \
        __syncthreads();                                                                \
        bf16x8 af[4], bf[4];                                                            \
        _Pragma("unroll") for (int mf = 0; mf < 4; ++mf)                                \
            af[mf] = *reinterpret_cast<const bf16x8*>(                                  \
                &As[(wr * 64 + mf * 16 + lr) * 32 + lh * 8]);                           \
        _Pragma("unroll") for (int nf = 0; nf < 4; ++nf)                                \
            bf[nf] = *reinterpret_cast<const bf16x8*>(                                  \
                &Bs[(wc * 64 + nf * 16 + lr) * 32 + lh * 8]);                           \
        _Pragma("unroll") for (int mf = 0; mf < 4; ++mf)                                \
            _Pragma("unroll") for (int nf = 0; nf < 4; ++nf)                            \
                acc[mf][nf] = mfma16(af[mf], bf[nf], acc[mf][nf]);                      \
        __syncthreads();                                                                \
    }

// ---- QKV GEMM ----
__global__ __launch_bounds__(256) void gemm_qkv_kernel(
    const __hip_bfloat16* __restrict__ A, const __hip_bfloat16* __restrict__ Bt,
    const float* __restrict__ bias,
    __hip_bfloat16* __restrict__ qd, __hip_bfloat16* __restrict__ kd,
    __hip_bfloat16* __restrict__ vtd) {
    const int K = 1024;
    const int m0 = blockIdx.x * 128;
    const int n0 = blockIdx.y * 128;
    GEMM128_BODY(A, Bt, K)

    const int region = n0 >> 10;  // 0:q 1:k 2:v (block-uniform)
#pragma unroll
    for (int mf = 0; mf < 4; ++mf) {
#pragma unroll
        for (int nf = 0; nf < 4; ++nf) {
            int n = n0 + wc * 64 + nf * 16 + lr;
            float bv = bias[n];
            int mbase = m0 + wr * 64 + mf * 16 + 4 * lh;
            int bb = mbase >> 11;
            int t = mbase & 2047;
            int c = n & 1023, hh = c >> 6, dd = c & 63;
            if (region == 2) {
                union { __hip_bfloat16 h[4]; uint2 v; } pk;
#pragma unroll
                for (int r = 0; r < 4; ++r) pk.h[r] = __float2bfloat16(acc[mf][nf][r] + bv);
                *reinterpret_cast<uint2*>(
                    &vtd[(((size_t)bb * 16 + hh) * 64 + dd) * 2048 + t]) = pk.v;
            } else if (region == 0) {
#pragma unroll
                for (int r = 0; r < 4; ++r)
                    qd[(((size_t)bb * 16 + hh) * 2048 + t + r) * 64 + dd] =
                        __float2bfloat16((acc[mf][nf][r] + bv) * QSCL);
            } else {
#pragma unroll
                for (int r = 0; r < 4; ++r)
                    kd[(((size_t)bb * 16 + hh) * 2048 + t + r) * 64 + dd] =
                        __float2bfloat16(acc[mf][nf][r] + bv);
            }
        }
    }
}

// ---- proj GEMM ----
__global__ __launch_bounds__(256) void gemm_proj_kernel(
    const __hip_bfloat16* __restrict__ A, const __hip_bfloat16* __restrict__ Bt,
    const float* __restrict__ bias, float* __restrict__ out) {
    const int K = 1024, N = 1024;
    const int m0 = blockIdx.x * 128;
    const int n0 = blockIdx.y * 128;
    GEMM128_BODY(A, Bt, K)

#pragma unroll
    for (int nf = 0; nf < 4; ++nf) {
        int n = n0 + wc * 64 + nf * 16 + lr;
        float bv = bias[n];
#pragma unroll
        for (int mf = 0; mf < 4; ++mf) {
            int mbase = m0 + wr * 64 + mf * 16 + 4 * lh;
#pragma unroll
            for (int r = 0; r < 4; ++r)
                out[(size_t)(mbase + r) * N + n] = acc[mf][nf][r] + bv;
        }
    }
}

// ---- causal flash attention v4 ----
// Block: 64 q rows (4 waves x 16), K/V 64-kv tiles staged in swizzled LDS.
// Balanced pairing over 32 q-tiles: block x does q-tiles x and 31-x (33 kv-tiles each).
// q pre-scaled by 0.125*log2e -> softmax in exp2 domain.
// Per-lane partial row-sums (reduced once per q-tile); defer-max THR=8.
__global__ __launch_bounds__(256) void attn_kernel(
    const __hip_bfloat16* __restrict__ q, const __hip_bfloat16* __restrict__ k,
    const __hip_bfloat16* __restrict__ vt, __hip_bfloat16* __restrict__ y) {
    const int T = 2048, D = 64, C = 1024;
    const float THR = 8.0f;
    int bh = blockIdx.y;
    int b = bh >> 4, h = bh & 15;
    int tid = threadIdx.x;
    int w = tid >> 6, l = tid & 63;
    int lr = l & 15, lh = l >> 4;

    __shared__ __hip_bfloat16 Ks[64 * 64];  // [kv][d], xor-swizzled rows
    __shared__ __hip_bfloat16 Vs[64 * 64];  // [d][kv], xor-swizzled rows
    __shared__ __hip_bfloat16 P[4][16][72];

    const __hip_bfloat16* kbh = k + (size_t)bh * T * D;
    const __hip_bfloat16* vbh = vt + (size_t)bh * D * T;

#pragma unroll
    for (int pp = 0; pp < 2; ++pp) {
        int qt = pp ? (31 - (int)blockIdx.x) : (int)blockIdx.x;
        int q0 = qt * 64 + w * 16;

        bf16x8 qa[2];
#pragma unroll
        for (int dd = 0; dd < 2; ++dd)
            qa[dd] = *reinterpret_cast<const bf16x8*>(
                q + ((size_t)bh * T + q0 + lr) * D + 32 * dd + 8 * lh);

        f32x4 zero = {0.f, 0.f, 0.f, 0.f};
        f32x4 o[4] = {zero, zero, zero, zero};
        float m[4], lp[4];
#pragma unroll
        for (int r = 0; r < 4; ++r) { m[r] = -INFINITY; lp[r] = 0.f; }

        int ntile = qt + 1;
        for (int t = 0; t < ntile; ++t) {
            int kv0 = t * 64;
            // ---- stage K and V tiles ----
#pragma unroll
            for (int j = 0; j < 2; ++j) {
                int slot = j * 256 + tid;
                int row = slot >> 3;
                int colb = ((slot & 7) * 16) ^ ((row & 7) << 4);
                async_copy16(kbh + (size_t)(kv0 + row) * 64 + (colb >> 1),
                             Ks + (size_t)(j * 256 + w * 64) * 8);
                async_copy16(vbh + (size_t)row * T + kv0 + (colb >> 1),
                             Vs + (size_t)(j * 256 + w * 64) * 8);
            }
            __syncthreads();

            // K frags from LDS (swizzled)
            bf16x8 kb[4][2];
#pragma unroll
            for (int ct = 0; ct < 4; ++ct)
#pragma unroll
                for (int dd = 0; dd < 2; ++dd) {
                    int row = 16 * ct + lr;
                    int colb = (dd * 64 + lh * 16) ^ ((lr & 7) << 4);
                    kb[ct][dd] = *reinterpret_cast<const bf16x8*>(
                        reinterpret_cast<const char*>(Ks) + row * 128 + colb);
                }

            f32x4 s[4];
#pragma unroll
            for (int ct = 0; ct < 4; ++ct) {
                f32x4 acc = zero;
                acc = mfma16(qa[0], kb[ct][0], acc);
                acc = mfma16(qa[1], kb[ct][1], acc);
                s[ct] = acc;
            }

            // V frags from LDS (swizzled) — issue early, latency hides under softmax
            bf16x8 vb[4][2];
#pragma unroll
            for (int dt = 0; dt < 4; ++dt)
#pragma unroll
                for (int kk = 0; kk < 2; ++kk) {
                    int row = 16 * dt + lr;
                    int colb = (kk * 64 + lh * 16) ^ ((lr & 7) << 4);
                    vb[dt][kk] = *reinterpret_cast<const bf16x8*>(
                        reinterpret_cast<const char*>(Vs) + row * 128 + colb);
                }

            // mask (diagonal tile only)
            if (t == qt) {
#pragma unroll
                for (int ct = 0; ct < 4; ++ct)
#pragma unroll
                    for (int r = 0; r < 4; ++r) {
                        int qq = q0 + 4 * lh + r;
                        int kc = kv0 + 16 * ct + lr;
                        if (kc > qq) s[ct][r] = -INFINITY;
                    }
            }

            // row max of tile
            float mx[4];
#pragma unroll
            for (int r = 0; r < 4; ++r)
                mx[r] = fmaxf(fmaxf(s[0][r], s[1][r]), fmaxf(s[2][r], s[3][r]));
#pragma unroll
            for (int d = 1; d < 16; d <<= 1)
#pragma unroll
                for (int r = 0; r < 4; ++r) mx[r] = fmaxf(mx[r], __shfl_xor(mx[r], d, 16));

            // defer-max: rescale only when growth exceeds THR
            bool small = (mx[0] - m[0] <= THR) && (mx[1] - m[1] <= THR) &&
                         (mx[2] - m[2] <= THR) && (mx[3] - m[3] <= THR);
            if (!__all(small)) {
#pragma unroll
                for (int r = 0; r < 4; ++r) {
                    float mnew = fmaxf(m[r], mx[r]);
                    float al = __builtin_amdgcn_exp2f(m[r] - mnew);
                    m[r] = mnew;
                    lp[r] *= al;
#pragma unroll
                    for (int dt = 0; dt < 4; ++dt) o[dt][r] *= al;
                }
            }

            // p = exp2(s - m); per-lane partial row sums
#pragma unroll
            for (int ct = 0; ct < 4; ++ct)
#pragma unroll
                for (int r = 0; r < 4; ++r)
                    s[ct][r] = __builtin_amdgcn_exp2f(s[ct][r] - m[r]);
#pragma unroll
            for (int r = 0; r < 4; ++r)
                lp[r] += (s[0][r] + s[1][r]) + (s[2][r] + s[3][r]);

            // pack P (wave-internal LDS, no barrier)
#pragma unroll
            for (int ct = 0; ct < 4; ++ct)
#pragma unroll
                for (int r = 0; r < 4; ++r)
                    P[w][4 * lh + r][16 * ct + lr] = __float2bfloat16(s[ct][r]);

            bf16x8 pa0 = *reinterpret_cast<const bf16x8*>(&P[w][lr][8 * lh]);
            bf16x8 pa1 = *reinterpret_cast<const bf16x8*>(&P[w][lr][32 + 8 * lh]);
#pragma unroll
            for (int dt = 0; dt < 4; ++dt) {
                o[dt] = mfma16(pa0, vb[dt][0], o[dt]);
                o[dt] = mfma16(pa1, vb[dt][1], o[dt]);
            }
            __syncthreads();
        }

        // reduce row sums across the 16 lanes, once per q-tile
#pragma unroll
        for (int d = 1; d < 16; d <<= 1)
#pragma unroll
            for (int r = 0; r < 4; ++r) lp[r] += __shfl_xor(lp[r], d, 16);

        float inv[4];
#pragma unroll
        for (int r = 0; r < 4; ++r) inv[r] = 1.0f / lp[r];
#pragma unroll
        for (int dt = 0; dt < 4; ++dt)
#pragma unroll
            for (int r = 0; r < 4; ++r) {
                int qq = q0 + 4 * lh + r;
                y[((size_t)b * T + qq) * C + h * 64 + dt * 16 + lr] =
                    __float2bfloat16(o[dt][r] * inv[r]);
            }
    }
}

extern "C" void kernel_launch(void* const* d_in, const int* in_sizes, int n_in,
                              void* d_out, int out_size, void* d_ws, size_t ws_size,
                              hipStream_t stream) {
    const float* x      = (const float*)d_in[0];
    const float* W_attn = (const float*)d_in[1];
    const float* b_attn = (const float*)d_in[2];
    const float* W_proj = (const float*)d_in[3];
    const float* b_proj = (const float*)d_in[4];
    float* out = (float*)d_out;

    __hip_bfloat16* wsb = reinterpret_cast<__hip_bfloat16*>(d_ws);
    __hip_bfloat16* xb  = wsb;                              // 8192*1024
    __hip_bfloat16* WaT = xb + (size_t)8192 * 1024;         // 3072*1024
    __hip_bfloat16* WpT = WaT + (size_t)3072 * 1024;        // 1024*1024
    __hip_bfloat16* qd  = WpT + (size_t)1024 * 1024;        // 64*2048*64
    __hip_bfloat16* kd  = qd + (size_t)64 * 2048 * 64;
    __hip_bfloat16* vtd = kd + (size_t)64 * 2048 * 64;
    __hip_bfloat16* ya  = vtd + (size_t)64 * 2048 * 64;     // 8192*1024

    cast_x_kernel<<<4096, 256, 0, stream>>>(x, xb, 8192 * 1024);
    transpose_cast_kernel<<<dim3(96, 32), 256, 0, stream>>>(W_attn, WaT, 1024, 3072);
    transpose_cast_kernel<<<dim3(32, 32), 256, 0, stream>>>(W_proj, WpT, 1024, 1024);
    gemm_qkv_kernel<<<dim3(64, 24), 256, 0, stream>>>(xb, WaT, b_attn, qd, kd, vtd);
    attn_kernel<<<dim3(16, 64), 256, 0, stream>>>(qd, kd, vtd, ya);
    gemm_proj_kernel<<<dim3(64, 8), 256, 0, stream>>>(ya, WpT, b_proj, out);
}